// Round 1
// 2847.565 us; speedup vs baseline: 1.2283x; 1.2283x over previous
//
#include <hip/hip_runtime.h>
#include <math.h>

#define B_  1024
#define T_  512
#define D_  30
#define H1_ 96
#define G1_ 384
#define H2_ 64
#define G2_ 256

// Inter-kernel buffers as device globals (.bss, bound at module load).
// Fully overwritten every call before being read (no cross-call state).
__device__ float g_h1[(size_t)B_ * T_ * 192];   // 384 MiB: layer-1 output
__device__ float g_h2f[(size_t)B_ * H2_];       // layer-2 fwd final state

__device__ __forceinline__ float fast_tanh(float v) {
  float a = fabsf(v);
  float e = __expf(-2.0f * a);
  float t = 1.0f - 2.0f * e / (1.0f + e);
  return v < 0.0f ? -t : t;
}
__device__ __forceinline__ float fast_sigmoid(float v) {
  return 0.5f + 0.5f * fast_tanh(0.5f * v);   // exact identity, overflow-safe
}

// ---------------------------------------------------------------------------
// Layer 1: bidirectional LSTM over x (B,T,30) -> g_h1 (B,T,192)
// grid (128, 2): blockIdx.x = batch tile of 8, blockIdx.y = dir.
// 768 threads = (gate-PAIR j = tid%192 owning rows j and j+192, k-quarter
// q = tid/192, wave-uniform). Each broadcast LDS read of v (4 k-values of one
// batch) now feeds 8 FMAs (2 gates) instead of 4 -> ds_read_b128 per
// CU-timestep halves 1536->768 (LDS pipe was the bottleneck: ~4.8cyc/b128
// broadcast * 1536 = ~7.4k of the 11.2k cycle/step budget).
// Unified input vec v[128]: [0:30)=x_t, [30:32)=0, [32:128)=h_{t-1}.
// ---------------------------------------------------------------------------
__global__ __launch_bounds__(768, 3)
void lstm1_kernel(const float* __restrict__ x,
                  const float* __restrict__ Wih_f, const float* __restrict__ Whh_f,
                  const float* __restrict__ bih_f, const float* __restrict__ bhh_f,
                  const float* __restrict__ Wih_b, const float* __restrict__ Whh_b,
                  const float* __restrict__ bih_b, const float* __restrict__ bhh_b)
{
  const int tid = threadIdx.x;
  const int dir = blockIdx.y;
  const int b0  = blockIdx.x * 8;

  const float* __restrict__ Wih = dir ? Wih_b : Wih_f;
  const float* __restrict__ Whh = dir ? Whh_b : Whh_f;
  const float* __restrict__ bih = dir ? bih_b : bih_f;
  const float* __restrict__ bhh = dir ? bhh_b : bhh_f;

  __shared__ __align__(16) float hx[8][128];     // [b][0:30 x | 32:128 h]
  __shared__ float gbuf[G1_ * 33];               // [row][b*4+q], stride 33: 2-way only

  const int j = tid % 192;                       // gate pair: rows j, j+192
  const int q = tid / 192;                       // k-quarter (wave-uniform: 192%64==0)

  // 16 NAMED float4 regs (SSA values -- cannot be demoted to scratch).
  // w0..w7 = row j, w8..w15 = row j+192, both over k in [32q, 32q+32).
  float4 w0,w1,w2,w3,w4,w5,w6,w7,w8,w9,w10,w11,w12,w13,w14,w15;
  if (q == 0) {                                  // k = 0..31: x-part (30 + 2 pad)
    const float* wa = Wih + j * D_;
    w0 = make_float4(wa[ 0], wa[ 1], wa[ 2], wa[ 3]);
    w1 = make_float4(wa[ 4], wa[ 5], wa[ 6], wa[ 7]);
    w2 = make_float4(wa[ 8], wa[ 9], wa[10], wa[11]);
    w3 = make_float4(wa[12], wa[13], wa[14], wa[15]);
    w4 = make_float4(wa[16], wa[17], wa[18], wa[19]);
    w5 = make_float4(wa[20], wa[21], wa[22], wa[23]);
    w6 = make_float4(wa[24], wa[25], wa[26], wa[27]);
    w7 = make_float4(wa[28], wa[29], 0.0f, 0.0f);
    const float* wb = Wih + (j + 192) * D_;
    w8  = make_float4(wb[ 0], wb[ 1], wb[ 2], wb[ 3]);
    w9  = make_float4(wb[ 4], wb[ 5], wb[ 6], wb[ 7]);
    w10 = make_float4(wb[ 8], wb[ 9], wb[10], wb[11]);
    w11 = make_float4(wb[12], wb[13], wb[14], wb[15]);
    w12 = make_float4(wb[16], wb[17], wb[18], wb[19]);
    w13 = make_float4(wb[20], wb[21], wb[22], wb[23]);
    w14 = make_float4(wb[24], wb[25], wb[26], wb[27]);
    w15 = make_float4(wb[28], wb[29], 0.0f, 0.0f);
  } else {                                       // k = 32q..32q+31: h-part
    const float4* ha = (const float4*)(Whh + j * H1_ + 32 * (q - 1));
    w0 = ha[0]; w1 = ha[1]; w2 = ha[2]; w3 = ha[3];
    w4 = ha[4]; w5 = ha[5]; w6 = ha[6]; w7 = ha[7];
    const float4* hb = (const float4*)(Whh + (j + 192) * H1_ + 32 * (q - 1));
    w8  = hb[0]; w9  = hb[1]; w10 = hb[2]; w11 = hb[3];
    w12 = hb[4]; w13 = hb[5]; w14 = hb[6]; w15 = hb[7];
  }

  // every thread is also a cell-updater: unit uj, batch ub (96*8 = 768)
  const int uj = tid % 96;
  const int ub = tid / 96;
  const float bias_i = bih[uj      ] + bhh[uj      ];
  const float bias_f = bih[uj +  96] + bhh[uj +  96];
  const float bias_g = bih[uj + 192] + bhh[uj + 192];
  const float bias_o = bih[uj + 288] + bhh[uj + 288];
  float c_state = 0.0f;

  for (int i = tid; i < 8 * 128; i += 768) (&hx[0][0])[i] = 0.0f;
  __syncthreads();
  const int xb = tid / 30;
  const int xd = tid - xb * 30;
  if (tid < 240) {
    const int t0 = dir ? (T_ - 1) : 0;
    hx[xb][xd] = x[((size_t)(b0 + xb) * T_ + t0) * D_ + xd];
  }
  __syncthreads();

  const int qoff = q * 8;                        // float4 index of k-quarter
  const float4* hx4 = (const float4*)(&hx[0][0]);

  for (int s = 0; s < T_; ++s) {
    const int t = dir ? (T_ - 1 - s) : s;
    float xn = 0.0f;
    if (tid < 240 && s + 1 < T_) {
      const int tn = dir ? (t - 1) : (t + 1);
      xn = x[((size_t)(b0 + xb) * T_ + tn) * D_ + xd];
    }
    float accA0=0.f, accA1=0.f, accA2=0.f, accA3=0.f;
    float accA4=0.f, accA5=0.f, accA6=0.f, accA7=0.f;
    float accB0=0.f, accB1=0.f, accB2=0.f, accB3=0.f;
    float accB4=0.f, accB5=0.f, accB6=0.f, accB7=0.f;
#define FB1(i, k) {                                                           \
    float4 v0 = hx4[0*32 + qoff + i]; float4 v1 = hx4[1*32 + qoff + i];       \
    float4 v2 = hx4[2*32 + qoff + i]; float4 v3 = hx4[3*32 + qoff + i];       \
    float4 v4 = hx4[4*32 + qoff + i]; float4 v5 = hx4[5*32 + qoff + i];       \
    float4 v6 = hx4[6*32 + qoff + i]; float4 v7 = hx4[7*32 + qoff + i];       \
    accA0 = fmaf(w##i.x, v0.x, accA0); accA0 = fmaf(w##i.y, v0.y, accA0);     \
    accA0 = fmaf(w##i.z, v0.z, accA0); accA0 = fmaf(w##i.w, v0.w, accA0);     \
    accB0 = fmaf(w##k.x, v0.x, accB0); accB0 = fmaf(w##k.y, v0.y, accB0);     \
    accB0 = fmaf(w##k.z, v0.z, accB0); accB0 = fmaf(w##k.w, v0.w, accB0);     \
    accA1 = fmaf(w##i.x, v1.x, accA1); accA1 = fmaf(w##i.y, v1.y, accA1);     \
    accA1 = fmaf(w##i.z, v1.z, accA1); accA1 = fmaf(w##i.w, v1.w, accA1);     \
    accB1 = fmaf(w##k.x, v1.x, accB1); accB1 = fmaf(w##k.y, v1.y, accB1);     \
    accB1 = fmaf(w##k.z, v1.z, accB1); accB1 = fmaf(w##k.w, v1.w, accB1);     \
    accA2 = fmaf(w##i.x, v2.x, accA2); accA2 = fmaf(w##i.y, v2.y, accA2);     \
    accA2 = fmaf(w##i.z, v2.z, accA2); accA2 = fmaf(w##i.w, v2.w, accA2);     \
    accB2 = fmaf(w##k.x, v2.x, accB2); accB2 = fmaf(w##k.y, v2.y, accB2);     \
    accB2 = fmaf(w##k.z, v2.z, accB2); accB2 = fmaf(w##k.w, v2.w, accB2);     \
    accA3 = fmaf(w##i.x, v3.x, accA3); accA3 = fmaf(w##i.y, v3.y, accA3);     \
    accA3 = fmaf(w##i.z, v3.z, accA3); accA3 = fmaf(w##i.w, v3.w, accA3);     \
    accB3 = fmaf(w##k.x, v3.x, accB3); accB3 = fmaf(w##k.y, v3.y, accB3);     \
    accB3 = fmaf(w##k.z, v3.z, accB3); accB3 = fmaf(w##k.w, v3.w, accB3);     \
    accA4 = fmaf(w##i.x, v4.x, accA4); accA4 = fmaf(w##i.y, v4.y, accA4);     \
    accA4 = fmaf(w##i.z, v4.z, accA4); accA4 = fmaf(w##i.w, v4.w, accA4);     \
    accB4 = fmaf(w##k.x, v4.x, accB4); accB4 = fmaf(w##k.y, v4.y, accB4);     \
    accB4 = fmaf(w##k.z, v4.z, accB4); accB4 = fmaf(w##k.w, v4.w, accB4);     \
    accA5 = fmaf(w##i.x, v5.x, accA5); accA5 = fmaf(w##i.y, v5.y, accA5);     \
    accA5 = fmaf(w##i.z, v5.z, accA5); accA5 = fmaf(w##i.w, v5.w, accA5);     \
    accB5 = fmaf(w##k.x, v5.x, accB5); accB5 = fmaf(w##k.y, v5.y, accB5);     \
    accB5 = fmaf(w##k.z, v5.z, accB5); accB5 = fmaf(w##k.w, v5.w, accB5);     \
    accA6 = fmaf(w##i.x, v6.x, accA6); accA6 = fmaf(w##i.y, v6.y, accA6);     \
    accA6 = fmaf(w##i.z, v6.z, accA6); accA6 = fmaf(w##i.w, v6.w, accA6);     \
    accB6 = fmaf(w##k.x, v6.x, accB6); accB6 = fmaf(w##k.y, v6.y, accB6);     \
    accB6 = fmaf(w##k.z, v6.z, accB6); accB6 = fmaf(w##k.w, v6.w, accB6);     \
    accA7 = fmaf(w##i.x, v7.x, accA7); accA7 = fmaf(w##i.y, v7.y, accA7);     \
    accA7 = fmaf(w##i.z, v7.z, accA7); accA7 = fmaf(w##i.w, v7.w, accA7);     \
    accB7 = fmaf(w##k.x, v7.x, accB7); accB7 = fmaf(w##k.y, v7.y, accB7);     \
    accB7 = fmaf(w##k.z, v7.z, accB7); accB7 = fmaf(w##k.w, v7.w, accB7); }
    FB1(0,8) FB1(1,9) FB1(2,10) FB1(3,11)
    FB1(4,12) FB1(5,13) FB1(6,14) FB1(7,15)
#undef FB1
    {
      const int ga = j * 33 + q;                 // lanes: j consecutive -> 2-way
      gbuf[ga +  0] = accA0; gbuf[ga +  4] = accA1;
      gbuf[ga +  8] = accA2; gbuf[ga + 12] = accA3;
      gbuf[ga + 16] = accA4; gbuf[ga + 20] = accA5;
      gbuf[ga + 24] = accA6; gbuf[ga + 28] = accA7;
      const int gbB = (j + 192) * 33 + q;
      gbuf[gbB +  0] = accB0; gbuf[gbB +  4] = accB1;
      gbuf[gbB +  8] = accB2; gbuf[gbB + 12] = accB3;
      gbuf[gbB + 16] = accB4; gbuf[gbB + 20] = accB5;
      gbuf[gbB + 24] = accB6; gbuf[gbB + 28] = accB7;
    }
    __syncthreads();
    if (tid < 240 && s + 1 < T_) hx[xb][xd] = xn;
    {
      const int ro = ub * 4;
      float gi = bias_i, gf = bias_f, gg = bias_g, go = bias_o;
#pragma unroll
      for (int qq = 0; qq < 4; ++qq) {
        gi += gbuf[(uj      ) * 33 + ro + qq];
        gf += gbuf[(uj +  96) * 33 + ro + qq];
        gg += gbuf[(uj + 192) * 33 + ro + qq];
        go += gbuf[(uj + 288) * 33 + ro + qq];
      }
      float iv = fast_sigmoid(gi);
      float fv = fast_sigmoid(gf);
      float ov = fast_sigmoid(go);
      c_state = fv * c_state + iv * fast_tanh(gg);
      float h = ov * fast_tanh(c_state);
      hx[ub][32 + uj] = h;
      g_h1[((size_t)(b0 + ub) * T_ + t) * 192 + dir * 96 + uj] = h;
    }
    __syncthreads();
  }
}

// ---------------------------------------------------------------------------
// Layer 2 forward scan: g_h1 (B,T,192) -> g_h2f (B,64).
// grid 256: 4 batch/block. 1024 threads = (gate-PAIR j = tid%128 owning rows
// j and j+128, k-eighth e = tid/128, wave-uniform). Each broadcast v read
// feeds 8 FMAs -> ds_read_b128 per CU-timestep halves 1024->512.
// v[256]: [0:192)=h1_t, [192:256)=h2_{t-1}.
// ---------------------------------------------------------------------------
__global__ __launch_bounds__(1024, 4)
void lstm2f_kernel(const float* __restrict__ Wih, const float* __restrict__ Whh,
                   const float* __restrict__ bih, const float* __restrict__ bhh)
{
  const int tid = threadIdx.x;
  const int b0  = blockIdx.x * 4;
  const int j   = tid % 128;                     // pair rows j, j+128
  const int e   = tid / 128;                     // k-eighth (wave-uniform)

  __shared__ __align__(16) float hx[4][256];     // [b][0:192 h1 | 192:256 h2prev]
  __shared__ float gbuf[G2_ * 33];               // [row][b*8+e], stride 33

  float4 w0,w1,w2,w3,w4,w5,w6,w7,w8,w9,w10,w11,w12,w13,w14,w15;
  {
    const float4* wa = (e < 6) ? (const float4*)(Wih + j * 192 + 32 * e)
                               : (const float4*)(Whh + j * H2_ + 32 * (e - 6));
    w0 = wa[0];  w1 = wa[1];  w2 = wa[2];  w3 = wa[3];
    w4 = wa[4];  w5 = wa[5];  w6 = wa[6];  w7 = wa[7];
    const float4* wb = (e < 6) ? (const float4*)(Wih + (j + 128) * 192 + 32 * e)
                               : (const float4*)(Whh + (j + 128) * H2_ + 32 * (e - 6));
    w8  = wb[0]; w9  = wb[1]; w10 = wb[2]; w11 = wb[3];
    w12 = wb[4]; w13 = wb[5]; w14 = wb[6]; w15 = wb[7];
  }

  const int uj = tid & 63;                       // updaters: tid < 256
  const int ub = (tid >> 6) & 3;
  const float bias_i = bih[uj      ] + bhh[uj      ];
  const float bias_f = bih[uj +  64] + bhh[uj +  64];
  const float bias_g = bih[uj + 128] + bhh[uj + 128];
  const float bias_o = bih[uj + 192] + bhh[uj + 192];
  float c_state = 0.0f;

  for (int i = tid; i < 4 * 256; i += 1024) (&hx[0][0])[i] = 0.0f;
  __syncthreads();
  const int pb = tid / 96;                       // h1 stagers: tid < 384
  const int pj = tid - pb * 96;
  if (tid < 384) {
    *(float2*)&hx[pb][pj * 2] =
        *(const float2*)&g_h1[((size_t)(b0 + pb) * T_ + 0) * 192 + pj * 2];
  }
  __syncthreads();

  const int eoff = e * 8;
  const float4* hx4 = (const float4*)(&hx[0][0]);

  for (int s = 0; s < T_; ++s) {
    float2 pre = make_float2(0.0f, 0.0f);
    if (tid < 384 && s + 1 < T_) {
      pre = *(const float2*)&g_h1[((size_t)(b0 + pb) * T_ + (s + 1)) * 192 + pj * 2];
    }
    float accA0=0.f, accA1=0.f, accA2=0.f, accA3=0.f;
    float accB0=0.f, accB1=0.f, accB2=0.f, accB3=0.f;
#define FB2(i, k) {                                                           \
    float4 v0 = hx4[0*64 + eoff + i]; float4 v1 = hx4[1*64 + eoff + i];       \
    float4 v2 = hx4[2*64 + eoff + i]; float4 v3 = hx4[3*64 + eoff + i];       \
    accA0 = fmaf(w##i.x, v0.x, accA0); accA0 = fmaf(w##i.y, v0.y, accA0);     \
    accA0 = fmaf(w##i.z, v0.z, accA0); accA0 = fmaf(w##i.w, v0.w, accA0);     \
    accB0 = fmaf(w##k.x, v0.x, accB0); accB0 = fmaf(w##k.y, v0.y, accB0);     \
    accB0 = fmaf(w##k.z, v0.z, accB0); accB0 = fmaf(w##k.w, v0.w, accB0);     \
    accA1 = fmaf(w##i.x, v1.x, accA1); accA1 = fmaf(w##i.y, v1.y, accA1);     \
    accA1 = fmaf(w##i.z, v1.z, accA1); accA1 = fmaf(w##i.w, v1.w, accA1);     \
    accB1 = fmaf(w##k.x, v1.x, accB1); accB1 = fmaf(w##k.y, v1.y, accB1);     \
    accB1 = fmaf(w##k.z, v1.z, accB1); accB1 = fmaf(w##k.w, v1.w, accB1);     \
    accA2 = fmaf(w##i.x, v2.x, accA2); accA2 = fmaf(w##i.y, v2.y, accA2);     \
    accA2 = fmaf(w##i.z, v2.z, accA2); accA2 = fmaf(w##i.w, v2.w, accA2);     \
    accB2 = fmaf(w##k.x, v2.x, accB2); accB2 = fmaf(w##k.y, v2.y, accB2);     \
    accB2 = fmaf(w##k.z, v2.z, accB2); accB2 = fmaf(w##k.w, v2.w, accB2);     \
    accA3 = fmaf(w##i.x, v3.x, accA3); accA3 = fmaf(w##i.y, v3.y, accA3);     \
    accA3 = fmaf(w##i.z, v3.z, accA3); accA3 = fmaf(w##i.w, v3.w, accA3);     \
    accB3 = fmaf(w##k.x, v3.x, accB3); accB3 = fmaf(w##k.y, v3.y, accB3);     \
    accB3 = fmaf(w##k.z, v3.z, accB3); accB3 = fmaf(w##k.w, v3.w, accB3); }
    FB2(0,8) FB2(1,9) FB2(2,10) FB2(3,11)
    FB2(4,12) FB2(5,13) FB2(6,14) FB2(7,15)
#undef FB2
    {
      const int ga = j * 33 + e;                 // lanes: j consecutive -> 2-way
      gbuf[ga +  0] = accA0; gbuf[ga +  8] = accA1;
      gbuf[ga + 16] = accA2; gbuf[ga + 24] = accA3;
      const int gbB = (j + 128) * 33 + e;
      gbuf[gbB +  0] = accB0; gbuf[gbB +  8] = accB1;
      gbuf[gbB + 16] = accB2; gbuf[gbB + 24] = accB3;
    }
    __syncthreads();
    if (tid < 384 && s + 1 < T_) *(float2*)&hx[pb][pj * 2] = pre;
    if (tid < 256) {
      const int ro = ub * 8;
      float gi = bias_i, gf = bias_f, gg = bias_g, go = bias_o;
#pragma unroll
      for (int ee = 0; ee < 8; ++ee) {
        gi += gbuf[(uj      ) * 33 + ro + ee];
        gf += gbuf[(uj +  64) * 33 + ro + ee];
        gg += gbuf[(uj + 128) * 33 + ro + ee];
        go += gbuf[(uj + 192) * 33 + ro + ee];
      }
      float iv = fast_sigmoid(gi), fv = fast_sigmoid(gf), ov = fast_sigmoid(go);
      c_state = fv * c_state + iv * fast_tanh(gg);
      float h = ov * fast_tanh(c_state);
      hx[ub][192 + uj] = h;
      if (s == T_ - 1) g_h2f[(b0 + ub) * H2_ + uj] = h;
    }
    __syncthreads();
  }
}

// ---------------------------------------------------------------------------
// Tail: layer-2 backward (ONE step from zero state on h1[:,T-1,:]) + dense
// head. grid 128 x 256 threads, 8 batch/block. (negligible runtime)
// ---------------------------------------------------------------------------
__global__ __launch_bounds__(256)
void tail_kernel(const float* __restrict__ Wih, const float* __restrict__ bih,
                 const float* __restrict__ bhh,
                 const float* __restrict__ W1, const float* __restrict__ b1,
                 const float* __restrict__ W2, const float* __restrict__ b2,
                 float* __restrict__ out)
{
  const int tid = threadIdx.x;
  const int b0  = blockIdx.x * 8;

  __shared__ __align__(16) float hl[8][192];    // h1 at t = T-1
  __shared__ float gb[G2_ * 9];
  __shared__ __align__(16) float last[8][128];  // [h2f | h2b]
  __shared__ float db[8][32];

  for (int i = tid; i < 8 * 96; i += 256) {
    int bb = i / 96, jj = i - (i / 96) * 96;
    *(float2*)&hl[bb][jj * 2] =
        *(const float2*)&g_h1[((size_t)(b0 + bb) * T_ + (T_ - 1)) * 192 + jj * 2];
  }
  for (int i = tid; i < 8 * 64; i += 256) {
    int bb = i >> 6, jj = i & 63;
    last[bb][jj] = g_h2f[(b0 + bb) * H2_ + jj];
  }
  __syncthreads();

  {
    const int gg_ = tid;
    const float* wr = Wih + gg_ * 192;
    const float bias = bih[gg_] + bhh[gg_];
    float acc[8];
#pragma unroll
    for (int b = 0; b < 8; ++b) acc[b] = bias;
#pragma unroll 4
    for (int qq = 0; qq < 48; ++qq) {
      float4 wv = *(const float4*)&wr[qq * 4];
#pragma unroll
      for (int b = 0; b < 8; ++b) {
        float4 v = *(const float4*)&hl[b][qq * 4];
        acc[b] = fmaf(wv.x, v.x, acc[b]);
        acc[b] = fmaf(wv.y, v.y, acc[b]);
        acc[b] = fmaf(wv.z, v.z, acc[b]);
        acc[b] = fmaf(wv.w, v.w, acc[b]);
      }
    }
#pragma unroll
    for (int b = 0; b < 8; ++b) gb[gg_ * 9 + b] = acc[b];
  }
  __syncthreads();

  for (int p = tid; p < 512; p += 256) {
    int jj = p & 63, bb = p >> 6;
    float gi = gb[(jj      ) * 9 + bb];
    float gg = gb[(jj + 128) * 9 + bb];
    float go = gb[(jj + 192) * 9 + bb];
    float c  = fast_sigmoid(gi) * fast_tanh(gg);
    float h  = fast_sigmoid(go) * fast_tanh(c);
    last[bb][64 + jj] = h;
  }
  __syncthreads();

  {
    int u = tid & 31, bb = tid >> 5;
    const float* wr1 = W1 + u * 128;
    float a = b1[u];
#pragma unroll
    for (int qq = 0; qq < 32; ++qq) {
      float4 wv = *(const float4*)&wr1[qq * 4];
      float4 v  = *(const float4*)&last[bb][qq * 4];
      a = fmaf(wv.x, v.x, a); a = fmaf(wv.y, v.y, a);
      a = fmaf(wv.z, v.z, a); a = fmaf(wv.w, v.w, a);
    }
    db[bb][u] = fmaxf(a, 0.0f);
  }
  __syncthreads();

  if (tid < 8) {
    float a = b2[0];
#pragma unroll
    for (int u2 = 0; u2 < 32; ++u2) a = fmaf(db[tid][u2], W2[u2], a);
    out[b0 + tid] = a;
  }
}

extern "C" void kernel_launch(void* const* d_in, const int* in_sizes, int n_in,
                              void* d_out, int out_size, void* d_ws, size_t ws_size,
                              hipStream_t stream)
{
  const float* x     = (const float*)d_in[0];
  const float* Wih1f = (const float*)d_in[1];
  const float* Whh1f = (const float*)d_in[2];
  const float* bih1f = (const float*)d_in[3];
  const float* bhh1f = (const float*)d_in[4];
  const float* Wih1b = (const float*)d_in[5];
  const float* Whh1b = (const float*)d_in[6];
  const float* bih1b = (const float*)d_in[7];
  const float* bhh1b = (const float*)d_in[8];
  const float* Wih2f = (const float*)d_in[9];
  const float* Whh2f = (const float*)d_in[10];
  const float* bih2f = (const float*)d_in[11];
  const float* bhh2f = (const float*)d_in[12];
  const float* Wih2b = (const float*)d_in[13];
  /* Whh2b (d_in[14]) unused: layer-2 backward at t=T-1 is one step from h=0 */
  const float* bih2b = (const float*)d_in[15];
  const float* bhh2b = (const float*)d_in[16];
  const float* W1    = (const float*)d_in[17];
  const float* b1    = (const float*)d_in[18];
  const float* W2    = (const float*)d_in[19];
  const float* b2    = (const float*)d_in[20];

  (void)d_ws; (void)ws_size; (void)in_sizes; (void)n_in; (void)out_size;

  lstm1_kernel<<<dim3(128, 2), 768, 0, stream>>>(
      x, Wih1f, Whh1f, bih1f, bhh1f, Wih1b, Whh1b, bih1b, bhh1b);
  lstm2f_kernel<<<256, 1024, 0, stream>>>(
      Wih2f, Whh2f, bih2f, bhh2f);
  tail_kernel<<<128, 256, 0, stream>>>(
      Wih2b, bih2b, bhh2b, W1, b1, W2, b2, (float*)d_out);
}